// Round 1
// baseline (3706.242 us; speedup 1.0000x reference)
//
#include <hip/hip_runtime.h>

// RuleGraphNet: 2x TripleConv(+mlp) on N=50000 nodes, E=800000 edges.
// Decomposition: concat-GEMM split into node-side transforms (NT, done once
// per conv as a dense GEMM) + edge-attr mid transform (fused in edge kernel)
// + gather/relu/atomic-scatter.

#define NN 50000
#define NE 800000
#define EHALF 400000
#define ED 100

// ---------------- generic fused GEMM: C = act(A@B + bias) ----------------
__global__ __launch_bounds__(256)
void gemm_bias_act(const float* __restrict__ A, const float* __restrict__ B,
                   const float* __restrict__ bias, float* __restrict__ C,
                   int M, int K, int Nc, int relu)
{
    __shared__ float As[32][68];   // [k][row], padded
    __shared__ float Bs[32][68];   // [k][col], padded
    const int t = threadIdx.x;
    const int tx = t & 15, ty = t >> 4;
    const int row0 = blockIdx.x * 64, col0 = blockIdx.y * 64;
    float acc[4][4] = {};
    for (int k0 = 0; k0 < K; k0 += 32) {
        for (int i = t; i < 2048; i += 256) {
            int r = i >> 5, kk = i & 31;
            int gr = row0 + r, gk = k0 + kk;
            As[kk][r] = (gr < M && gk < K) ? A[(size_t)gr * K + gk] : 0.f;
        }
        for (int i = t; i < 2048; i += 256) {
            int kk = i >> 6, c = i & 63;
            int gk = k0 + kk, gc = col0 + c;
            Bs[kk][c] = (gk < K && gc < Nc) ? B[(size_t)gk * Nc + gc] : 0.f;
        }
        __syncthreads();
        #pragma unroll
        for (int kk = 0; kk < 32; kk++) {
            float4 av = *(const float4*)&As[kk][ty * 4];
            float4 bv = *(const float4*)&Bs[kk][tx * 4];
            float a[4] = {av.x, av.y, av.z, av.w};
            float b[4] = {bv.x, bv.y, bv.z, bv.w};
            #pragma unroll
            for (int i = 0; i < 4; i++)
                #pragma unroll
                for (int j = 0; j < 4; j++)
                    acc[i][j] = fmaf(a[i], b[j], acc[i][j]);
        }
        __syncthreads();
    }
    #pragma unroll
    for (int i = 0; i < 4; i++) {
        int gr = row0 + ty * 4 + i;
        if (gr >= M) continue;
        #pragma unroll
        for (int j = 0; j < 4; j++) {
            int gc = col0 + tx * 4 + j;
            if (gc >= Nc) continue;
            float v = acc[i][j] + bias[gc];
            if (relu) v = fmaxf(v, 0.f);
            C[(size_t)gr * Nc + gc] = v;
        }
    }
}

// ---------------- edge kernel ----------------
// For edges [e_begin,e_end):
//   m = relu( e@Wmid  +  NT[dst][blk_dst..]  +  NT[src][blk_src..] )
//   atomicAdd(aggr[dst], m)
// Bias is pre-folded into the blk_dst block of NT.
template<int ND>   // node dim: 107 (conv1) or 100 (conv2)
__global__ __launch_bounds__(256)
void edge_conv(const float* __restrict__ eattr,   // [E][100]
               const int* __restrict__ eidx,      // [2][E]: row0=src, row1=dst
               const float* __restrict__ Wmid,    // [100][ND]
               const float* __restrict__ NT,      // [N][NTs]
               float* __restrict__ aggr,          // [N][ND]
               int e_begin, int e_end, int blk_dst, int blk_src, int NTs)
{
    __shared__ float Wl[100 * 128];   // 51.2 KB, cols zero-padded to 128
    __shared__ float et[32 * ED];     // 12.8 KB, 32 edges x 100
    const int t = threadIdx.x;
    for (int i = t; i < 100 * 128; i += 256) {
        int k = i >> 7, c = i & 127;
        Wl[i] = (c < ND) ? Wmid[k * ND + c] : 0.f;
    }
    const int tx = t & 15, ty = t >> 4;
    const int ntiles = (e_end - e_begin + 31) >> 5;
    for (int tile = blockIdx.x; tile < ntiles; tile += gridDim.x) {
        const int eb = e_begin + (tile << 5);
        __syncthreads();   // protect et (and first-iter Wl)
        for (int i = t; i < 800; i += 256) {   // 32*100/4 float4 loads
            int el = i / 25, kq = i % 25;
            int e = eb + el;
            float4 v = {0.f, 0.f, 0.f, 0.f};
            if (e < e_end) v = *(const float4*)(eattr + (size_t)e * ED + kq * 4);
            *(float4*)(et + el * ED + kq * 4) = v;
        }
        __syncthreads();
        // 32 edges x 128 cols GEMM tile: thread = (ty: 2 edges, tx: cols {tx*4..+3, 64+tx*4..+3})
        float acc[2][8] = {};
        for (int k = 0; k < ED; k += 4) {
            float ev[2][4];
            #pragma unroll
            for (int i = 0; i < 2; i++) {
                float4 v = *(const float4*)(et + (ty * 2 + i) * ED + k);
                ev[i][0] = v.x; ev[i][1] = v.y; ev[i][2] = v.z; ev[i][3] = v.w;
            }
            #pragma unroll
            for (int kk = 0; kk < 4; kk++) {
                float4 w0 = *(const float4*)(Wl + (k + kk) * 128 + tx * 4);
                float4 w1 = *(const float4*)(Wl + (k + kk) * 128 + 64 + tx * 4);
                float wv[8] = {w0.x, w0.y, w0.z, w0.w, w1.x, w1.y, w1.z, w1.w};
                #pragma unroll
                for (int i = 0; i < 2; i++)
                    #pragma unroll
                    for (int j = 0; j < 8; j++)
                        acc[i][j] = fmaf(ev[i][kk], wv[j], acc[i][j]);
            }
        }
        #pragma unroll
        for (int i = 0; i < 2; i++) {
            int e = eb + ty * 2 + i;
            if (e >= e_end) continue;
            int s = eidx[e];
            int d = eidx[NE + e];
            const float* ni = NT + (size_t)d * NTs + blk_dst;
            const float* nj = NT + (size_t)s * NTs + blk_src;
            float* ar = aggr + (size_t)d * ND;
            #pragma unroll
            for (int j = 0; j < 8; j++) {
                int c = (j < 4) ? (tx * 4 + j) : (64 + tx * 4 + (j - 4));
                if (c < ND) {
                    float v = acc[i][j] + ni[c] + nj[c];
                    atomicAdd(ar + c, fmaxf(v, 0.f));
                }
            }
        }
    }
}

// ---------------- weight assembly ----------------
// Wcat1[107][428] = [Wa_rows0-106 | Wa_rows207-313 | Wb_rows0-106 | Wb_rows207-313]
// bias1[428]      = [ba | 0 | 0 | bb]   (bias folded into the dst-side block)
// Wcat2[100][400], bias2[400] analogous with row offsets 200.
__global__ void assemble(const float* __restrict__ l1a, const float* __restrict__ l1ab,
                         const float* __restrict__ l1b, const float* __restrict__ l1bb,
                         const float* __restrict__ l2a, const float* __restrict__ l2ab,
                         const float* __restrict__ l2b, const float* __restrict__ l2bb,
                         float* __restrict__ W1, float* __restrict__ b1,
                         float* __restrict__ W2, float* __restrict__ b2)
{
    int i = blockIdx.x * 256 + threadIdx.x;
    if (i < 107 * 428) {
        int k = i / 428, c = i % 428;
        float v;
        if (c < 107)      v = l1a[k * 107 + c];
        else if (c < 214) v = l1a[(207 + k) * 107 + (c - 107)];
        else if (c < 321) v = l1b[k * 107 + (c - 214)];
        else              v = l1b[(207 + k) * 107 + (c - 321)];
        W1[i] = v;
    }
    if (i < 428) b1[i] = (i < 107) ? l1ab[i] : ((i >= 321) ? l1bb[i - 321] : 0.f);
    if (i < 100 * 400) {
        int k = i / 400, c = i % 400;
        float v;
        if (c < 100)      v = l2a[k * 100 + c];
        else if (c < 200) v = l2a[(200 + k) * 100 + (c - 100)];
        else if (c < 300) v = l2b[k * 100 + (c - 200)];
        else              v = l2b[(200 + k) * 100 + (c - 300)];
        W2[i] = v;
    }
    if (i < 400) b2[i] = (i < 100) ? l2ab[i] : ((i >= 300) ? l2bb[i - 300] : 0.f);
}

__global__ void copy4(const float4* __restrict__ in, float4* __restrict__ out, int n4)
{
    int i = blockIdx.x * 256 + threadIdx.x;
    if (i < n4) out[i] = in[i];
}

extern "C" void kernel_launch(void* const* d_in, const int* in_sizes, int n_in,
                              void* d_out, int out_size, void* d_ws, size_t ws_size,
                              hipStream_t stream)
{
    const float* x    = (const float*)d_in[0];
    const int*   eidx = (const int*)d_in[1];
    const float* eatt = (const float*)d_in[2];
    const float* l1aw = (const float*)d_in[3];
    const float* l1ab = (const float*)d_in[4];
    const float* l1bw = (const float*)d_in[5];
    const float* l1bb = (const float*)d_in[6];
    const float* m1w1 = (const float*)d_in[7];
    const float* m1b1 = (const float*)d_in[8];
    const float* m1w2 = (const float*)d_in[9];
    const float* m1b2 = (const float*)d_in[10];
    const float* l2aw = (const float*)d_in[11];
    const float* l2ab = (const float*)d_in[12];
    const float* l2bw = (const float*)d_in[13];
    const float* l2bb = (const float*)d_in[14];
    const float* m2w1 = (const float*)d_in[15];
    const float* m2b1 = (const float*)d_in[16];
    const float* m2w2 = (const float*)d_in[17];
    const float* m2b2 = (const float*)d_in[18];
    float* out = (float*)d_out;

    // workspace layout (floats):
    //   NT   : 50000*428           (node transforms, reused conv1/conv2)
    //   bufB : 5,350,000           (aggr1 -> h -> t2)
    //   bufC : 5,000,000           (t1 -> aggr2)
    //   Wcat1/bias1/Wcat2/bias2
    float* ws   = (float*)d_ws;
    float* NT   = ws;
    float* bufB = NT + (size_t)50000 * 428;
    float* bufC = bufB + 5350000;
    float* W1   = bufC + 5000000;
    float* b1v  = W1 + 45824;
    float* W2   = b1v + 448;
    float* b2v  = W2 + 40000;

    assemble<<<179, 256, 0, stream>>>(l1aw, l1ab, l1bw, l1bb, l2aw, l2ab, l2bw, l2bb,
                                      W1, b1v, W2, b2v);

    // ---- conv1 ----
    // aggr1 = x  (the "+ (1+eps)*x" term, eps=0)
    copy4<<<(1337500 + 255) / 256, 256, 0, stream>>>((const float4*)x, (float4*)bufB, 1337500);
    // NT1 = x @ Wcat1 + biascat1
    dim3 gNT1((NN + 63) / 64, (428 + 63) / 64);
    gemm_bias_act<<<gNT1, 256, 0, stream>>>(x, W1, b1v, NT, NN, 107, 428, 0);
    // edge halves (first half uses lin1a, second half lin1b with swapped i/j)
    edge_conv<107><<<12500, 256, 0, stream>>>(eatt, eidx, l1aw + 107 * 107, NT, bufB,
                                              0, EHALF, 0, 107, 428);
    edge_conv<107><<<12500, 256, 0, stream>>>(eatt, eidx, l1bw + 107 * 107, NT, bufB,
                                              EHALF, NE, 321, 214, 428);
    // mlp1: t1 = relu(aggr1@w1+b1); h = relu(t1@w2+b2)  (incl. inter-conv relu)
    dim3 gM1((NN + 63) / 64, 2);
    gemm_bias_act<<<gM1, 256, 0, stream>>>(bufB, m1w1, m1b1, bufC, NN, 107, 100, 1);
    gemm_bias_act<<<gM1, 256, 0, stream>>>(bufC, m1w2, m1b2, bufB, NN, 100, 100, 1);

    // ---- conv2 ----  (h lives in bufB)
    // aggr2 = h
    copy4<<<(1250000 + 255) / 256, 256, 0, stream>>>((const float4*)bufB, (float4*)bufC, 1250000);
    // NT2 = h @ Wcat2 + biascat2
    dim3 gNT2((NN + 63) / 64, (400 + 63) / 64);
    gemm_bias_act<<<gNT2, 256, 0, stream>>>(bufB, W2, b2v, NT, NN, 100, 400, 0);
    edge_conv<100><<<12500, 256, 0, stream>>>(eatt, eidx, l2aw + 100 * 100, NT, bufC,
                                              0, EHALF, 0, 100, 400);
    edge_conv<100><<<12500, 256, 0, stream>>>(eatt, eidx, l2bw + 100 * 100, NT, bufC,
                                              EHALF, NE, 300, 200, 400);
    // mlp2: t2 = relu(aggr2@w1+b1); out = t2@w2+b2
    dim3 gM2a((NN + 63) / 64, 1);
    gemm_bias_act<<<gM2a, 256, 0, stream>>>(bufC, m2w1, m2b1, bufB, NN, 100, 64, 1);
    dim3 gM2b((NN + 63) / 64, 2);
    gemm_bias_act<<<gM2b, 256, 0, stream>>>(bufB, m2w2, m2b2, out, NN, 64, 100, 0);
}

// Round 2
// 2265.460 us; speedup vs baseline: 1.6360x; 1.6360x over previous
//
#include <hip/hip_runtime.h>
#include <hip/hip_bf16.h>

// RuleGraphNet: 2x TripleConv(+mlp), N=50000 nodes, E=800000 edges.
// concat-GEMM split into node transforms (dense GEMM, padded 16B-aligned
// blocks) + per-edge mid transform. Edges are CSR-sorted by dst each call so
// aggregation uses LDS accumulation + single coalesced write (no global atomics).

#define NN 50000
#define NE 800000
#define EHALF 400000
#define NN2 100000
#define RPB 12          // dst nodes per block in edge pass

__device__ __forceinline__ float bfhi(unsigned u) {  // high 16 bits as bf16
    union { unsigned u; float f; } c; c.u = u & 0xffff0000u; return c.f;
}
__device__ __forceinline__ float bflo(unsigned u) {  // low 16 bits as bf16
    union { unsigned u; float f; } c; c.u = u << 16; return c.f;
}

// ---------------- generic fused GEMM: C = act(A@B + bias) ----------------
__global__ __launch_bounds__(256)
void gemm_bias_act(const float* __restrict__ A, const float* __restrict__ B,
                   const float* __restrict__ bias, float* __restrict__ C,
                   int M, int K, int Nc, int relu)
{
    __shared__ float As[32][68];
    __shared__ float Bs[32][68];
    const int t = threadIdx.x;
    const int tx = t & 15, ty = t >> 4;
    const int row0 = blockIdx.x * 64, col0 = blockIdx.y * 64;
    float acc[4][4] = {};
    for (int k0 = 0; k0 < K; k0 += 32) {
        for (int i = t; i < 2048; i += 256) {
            int r = i >> 5, kk = i & 31;
            int gr = row0 + r, gk = k0 + kk;
            As[kk][r] = (gr < M && gk < K) ? A[(size_t)gr * K + gk] : 0.f;
        }
        for (int i = t; i < 2048; i += 256) {
            int kk = i >> 6, c = i & 63;
            int gk = k0 + kk, gc = col0 + c;
            Bs[kk][c] = (gk < K && gc < Nc) ? B[(size_t)gk * Nc + gc] : 0.f;
        }
        __syncthreads();
        #pragma unroll
        for (int kk = 0; kk < 32; kk++) {
            float4 av = *(const float4*)&As[kk][ty * 4];
            float4 bv = *(const float4*)&Bs[kk][tx * 4];
            float a[4] = {av.x, av.y, av.z, av.w};
            float b[4] = {bv.x, bv.y, bv.z, bv.w};
            #pragma unroll
            for (int i = 0; i < 4; i++)
                #pragma unroll
                for (int j = 0; j < 4; j++)
                    acc[i][j] = fmaf(a[i], b[j], acc[i][j]);
        }
        __syncthreads();
    }
    #pragma unroll
    for (int i = 0; i < 4; i++) {
        int gr = row0 + ty * 4 + i;
        if (gr >= M) continue;
        #pragma unroll
        for (int j = 0; j < 4; j++) {
            int gc = col0 + tx * 4 + j;
            if (gc >= Nc) continue;
            float v = acc[i][j] + bias[gc];
            if (relu) v = fmaxf(v, 0.f);
            C[(size_t)gr * Nc + gc] = v;
        }
    }
}

// ---------------- CSR build (each call; edges sorted by dst, per half) ----
__global__ void zero_ints(int* __restrict__ p, int n)
{
    int i = blockIdx.x * 256 + threadIdx.x;
    if (i < n) p[i] = 0;
}

__global__ void count_edges(const int* __restrict__ dst, int* __restrict__ cnt)
{
    int e = blockIdx.x * 256 + threadIdx.x;
    if (e < NE) atomicAdd(&cnt[dst[e] + (e >= EHALF ? NN : 0)], 1);
}

__global__ void scan_blocks(const int* __restrict__ cnt, int* __restrict__ off,
                            int* __restrict__ bsum, int n)
{
    __shared__ int s[256];
    int t = threadIdx.x, g = blockIdx.x * 256 + t;
    int v = (g < n) ? cnt[g] : 0;
    s[t] = v; __syncthreads();
    for (int d = 1; d < 256; d <<= 1) {
        int add = (t >= d) ? s[t - d] : 0;
        __syncthreads();
        s[t] += add;
        __syncthreads();
    }
    if (g < n) off[g] = s[t] - v;
    if (t == 255) bsum[blockIdx.x] = s[255];
}

__global__ void scan_bsum(int* __restrict__ bsum, int nb)
{
    __shared__ int s[512];
    int t = threadIdx.x;
    int v = (t < nb) ? bsum[t] : 0;
    s[t] = v; __syncthreads();
    for (int d = 1; d < 512; d <<= 1) {
        int add = (t >= d) ? s[t - d] : 0;
        __syncthreads();
        s[t] += add;
        __syncthreads();
    }
    if (t < nb) bsum[t] = s[t] - v;
}

__global__ void scan_add(int* __restrict__ off, const int* __restrict__ bsum,
                         int* __restrict__ cur, int n)
{
    int g = blockIdx.x * 256 + threadIdx.x;
    if (g < n) { int o = off[g] + bsum[blockIdx.x]; off[g] = o; cur[g] = o; }
}

__global__ void scatter_edges(const int* __restrict__ dst, int* __restrict__ cur,
                              int* __restrict__ perm)
{
    int e = blockIdx.x * 256 + threadIdx.x;
    if (e < NE) {
        int pos = atomicAdd(&cur[dst[e] + (e >= EHALF ? NN : 0)], 1);
        perm[pos] = e;
    }
}

// ---------------- edge pass ----------------
// Block owns RPB consecutive dst nodes (CSR range). For each edge:
//   m = relu( e@Wmid + NT[dst][blk_dst..] + NT[src][blk_src..] )
// accumulated in LDS by local node; one coalesced write per node at the end.
// addmode 0: aggr = acc + self ; addmode 1: aggr += acc.
__global__ __launch_bounds__(256)
void edge_pass(const float* __restrict__ eattr,   // [E][100]
               const int* __restrict__ eidx,      // [2][E]
               const int* __restrict__ perm,
               const int* __restrict__ off,       // [NN2] exclusive offsets
               const float* __restrict__ Wmid,    // [100][ND] tight
               const float* __restrict__ NT,      // [NN][NTS] padded blocks
               const float* __restrict__ self,    // [NN][ND]
               float* __restrict__ aggr,          // [NN][ND]
               int half, int blk_dst, int blk_src, int NTS, int ND, int addmode)
{
    __shared__ __align__(16) float Wl[100 * 128];     // 51.2 KB (pad cols = 0)
    __shared__ __align__(16) short et[32 * 104];      // 6.5 KB bf16 edge attrs
    __shared__ __align__(16) float accl[RPB * 128];   // 6 KB accumulator
    __shared__ int eid[32], edst[32];
    const int t = threadIdx.x;
    for (int i = t; i < 100 * 128; i += 256) {
        int k = i >> 7, c = i & 127;
        Wl[i] = (c < ND) ? Wmid[k * ND + c] : 0.f;
    }
    for (int i = t; i < RPB * 128; i += 256) accl[i] = 0.f;
    const int n0 = blockIdx.x * RPB;
    const int nodes = min(RPB, NN - n0);
    const int base = half * NN + n0;
    const int p0 = off[base];
    const int p1 = (base + nodes == NN2) ? NE : off[base + nodes];
    const int tx = t & 31, ty = t >> 5;
    const int r0 = ty * 4;

    for (int pt = p0; pt < p1; pt += 32) {
        __syncthreads();               // protect et/eid reuse (and first Wl/accl)
        if (t < 32) {
            int p = pt + t;
            int e = (p < p1) ? perm[p] : -1;
            eid[t] = e;
            edst[t] = (e >= 0) ? eidx[NE + e] : -1;
        }
        __syncthreads();
        // stage 32 edges' attrs as bf16
        for (int i = t; i < 800; i += 256) {      // 32 edges x 25 quads
            int el = i & 31, q = i >> 5;
            int e = eid[el];
            float4 v = {0.f, 0.f, 0.f, 0.f};
            if (e >= 0) v = *(const float4*)(eattr + (size_t)e * 100 + q * 4);
            __hip_bfloat16 b[4] = {__float2bfloat16(v.x), __float2bfloat16(v.y),
                                   __float2bfloat16(v.z), __float2bfloat16(v.w)};
            *(short4*)(et + el * 104 + q * 4) = *(short4*)b;
        }
        __syncthreads();

        // NT gathers for this thread's 4 edges (prefetched before k-loop)
        int myd[4];
        float4 ni[4], nj[4];
        #pragma unroll
        for (int i = 0; i < 4; i++) {
            int e = eid[r0 + i];
            int d = edst[r0 + i];
            myd[i] = d;
            float4 z = {0.f, 0.f, 0.f, 0.f};
            ni[i] = z; nj[i] = z;
            if (e >= 0 && tx < 27) {
                int s = eidx[e];
                ni[i] = *(const float4*)(NT + (size_t)d * NTS + blk_dst + tx * 4);
                nj[i] = *(const float4*)(NT + (size_t)s * NTS + blk_src + tx * 4);
            }
        }
        // GEMM: 4 edges x 4 cols per thread
        float acc[4][4] = {};
        for (int k = 0; k < 100; k += 4) {
            float4 w0 = *(const float4*)(Wl + (k + 0) * 128 + tx * 4);
            float4 w1 = *(const float4*)(Wl + (k + 1) * 128 + tx * 4);
            float4 w2 = *(const float4*)(Wl + (k + 2) * 128 + tx * 4);
            float4 w3 = *(const float4*)(Wl + (k + 3) * 128 + tx * 4);
            #pragma unroll
            for (int i = 0; i < 4; i++) {
                uint2 ev = *(const uint2*)(et + (r0 + i) * 104 + k);
                float e0 = bflo(ev.x), e1 = bfhi(ev.x);
                float e2 = bflo(ev.y), e3 = bfhi(ev.y);
                acc[i][0] = fmaf(e0, w0.x, acc[i][0]); acc[i][1] = fmaf(e0, w0.y, acc[i][1]);
                acc[i][2] = fmaf(e0, w0.z, acc[i][2]); acc[i][3] = fmaf(e0, w0.w, acc[i][3]);
                acc[i][0] = fmaf(e1, w1.x, acc[i][0]); acc[i][1] = fmaf(e1, w1.y, acc[i][1]);
                acc[i][2] = fmaf(e1, w1.z, acc[i][2]); acc[i][3] = fmaf(e1, w1.w, acc[i][3]);
                acc[i][0] = fmaf(e2, w2.x, acc[i][0]); acc[i][1] = fmaf(e2, w2.y, acc[i][1]);
                acc[i][2] = fmaf(e2, w2.z, acc[i][2]); acc[i][3] = fmaf(e2, w2.w, acc[i][3]);
                acc[i][0] = fmaf(e3, w3.x, acc[i][0]); acc[i][1] = fmaf(e3, w3.y, acc[i][1]);
                acc[i][2] = fmaf(e3, w3.z, acc[i][2]); acc[i][3] = fmaf(e3, w3.w, acc[i][3]);
            }
        }
        // relu + in-register merge of same-dst runs + LDS accumulate
        if (tx < 27) {
            float4 run = {0.f, 0.f, 0.f, 0.f};
            int rd = -1;
            #pragma unroll
            for (int i = 0; i < 4; i++) {
                if (myd[i] < 0) continue;
                float4 m;
                m.x = fmaxf(acc[i][0] + ni[i].x + nj[i].x, 0.f);
                m.y = fmaxf(acc[i][1] + ni[i].y + nj[i].y, 0.f);
                m.z = fmaxf(acc[i][2] + ni[i].z + nj[i].z, 0.f);
                m.w = fmaxf(acc[i][3] + ni[i].w + nj[i].w, 0.f);
                if (myd[i] == rd) {
                    run.x += m.x; run.y += m.y; run.z += m.z; run.w += m.w;
                } else {
                    if (rd >= 0) {
                        float* a = accl + (rd - n0) * 128 + tx * 4;
                        atomicAdd(a + 0, run.x); atomicAdd(a + 1, run.y);
                        atomicAdd(a + 2, run.z); atomicAdd(a + 3, run.w);
                    }
                    rd = myd[i]; run = m;
                }
            }
            if (rd >= 0) {
                float* a = accl + (rd - n0) * 128 + tx * 4;
                atomicAdd(a + 0, run.x); atomicAdd(a + 1, run.y);
                atomicAdd(a + 2, run.z); atomicAdd(a + 3, run.w);
            }
        }
    }
    __syncthreads();
    const int tot = nodes * ND;
    for (int i = t; i < tot; i += 256) {
        int n = i / ND, c = i - n * ND;
        float v = accl[n * 128 + c];
        size_t gi = (size_t)(n0 + n) * ND + c;
        if (addmode == 0) aggr[gi] = v + self[gi];
        else              aggr[gi] += v;
    }
}

// ---------------- weight assembly (padded, 16B-aligned column blocks) -----
// W1p[107][432]: blocks at {0,108,216,324} = {Wa[0:107], Wa[207:314], Wb[0:107], Wb[207:314]}
// b1p[432] = {ba,0,0,bb};  W2p[100][416]: blocks {0,104,208,312}, b2p analogous.
__global__ void assemble(const float* __restrict__ l1a, const float* __restrict__ l1ab,
                         const float* __restrict__ l1b, const float* __restrict__ l1bb,
                         const float* __restrict__ l2a, const float* __restrict__ l2ab,
                         const float* __restrict__ l2b, const float* __restrict__ l2bb,
                         float* __restrict__ W1, float* __restrict__ b1,
                         float* __restrict__ W2, float* __restrict__ b2)
{
    int i = blockIdx.x * 256 + threadIdx.x;
    if (i < 107 * 432) {
        int k = i / 432, c = i % 432;
        int q = c / 108, cc = c - q * 108;
        float v = 0.f;
        if (cc < 107) {
            if (q == 0)      v = l1a[k * 107 + cc];
            else if (q == 1) v = l1a[(207 + k) * 107 + cc];
            else if (q == 2) v = l1b[k * 107 + cc];
            else             v = l1b[(207 + k) * 107 + cc];
        }
        W1[i] = v;
    }
    if (i < 432) {
        int q = i / 108, cc = i - q * 108;
        b1[i] = (cc < 107) ? (q == 0 ? l1ab[cc] : (q == 3 ? l1bb[cc] : 0.f)) : 0.f;
    }
    if (i < 100 * 416) {
        int k = i / 416, c = i % 416;
        int q = c / 104, cc = c - q * 104;
        float v = 0.f;
        if (cc < 100) {
            if (q == 0)      v = l2a[k * 100 + cc];
            else if (q == 1) v = l2a[(200 + k) * 100 + cc];
            else if (q == 2) v = l2b[k * 100 + cc];
            else             v = l2b[(200 + k) * 100 + cc];
        }
        W2[i] = v;
    }
    if (i < 416) {
        int q = i / 104, cc = i - q * 104;
        b2[i] = (cc < 100) ? (q == 0 ? l2ab[cc] : (q == 3 ? l2bb[cc] : 0.f)) : 0.f;
    }
}

extern "C" void kernel_launch(void* const* d_in, const int* in_sizes, int n_in,
                              void* d_out, int out_size, void* d_ws, size_t ws_size,
                              hipStream_t stream)
{
    const float* x    = (const float*)d_in[0];
    const int*   eidx = (const int*)d_in[1];
    const float* eatt = (const float*)d_in[2];
    const float* l1aw = (const float*)d_in[3];
    const float* l1ab = (const float*)d_in[4];
    const float* l1bw = (const float*)d_in[5];
    const float* l1bb = (const float*)d_in[6];
    const float* m1w1 = (const float*)d_in[7];
    const float* m1b1 = (const float*)d_in[8];
    const float* m1w2 = (const float*)d_in[9];
    const float* m1b2 = (const float*)d_in[10];
    const float* l2aw = (const float*)d_in[11];
    const float* l2ab = (const float*)d_in[12];
    const float* l2bw = (const float*)d_in[13];
    const float* l2bb = (const float*)d_in[14];
    const float* m2w1 = (const float*)d_in[15];
    const float* m2b1 = (const float*)d_in[16];
    const float* m2w2 = (const float*)d_in[17];
    const float* m2b2 = (const float*)d_in[18];
    float* out = (float*)d_out;

    // workspace layout (4-byte units)
    float* ws   = (float*)d_ws;
    float* NT   = ws;                                   // 50000*432 = 21,600,000
    float* bufA = NT + (size_t)50000 * 432;             // 5,350,000 (aggr1, aggr2)
    float* bufB = bufA + 5350000;                       // 5,000,000 (t1, t2)
    float* bufC = bufB + 5000000;                       // 5,000,000 (h)
    float* W1   = bufC + 5000000;                       // 46,224
    float* b1v  = W1 + 46224;                           // 432
    float* W2   = b1v + 432;                            // 41,600
    float* b2v  = W2 + 41600;                           // 416
    int*   off  = (int*)(b2v + 416);                    // 100,000
    int*   cur  = off + NN2;                            // 100,000
    int*   bsum = cur + NN2;                            // 512
    int*   perm = bsum + 512;                           // 800,000

    const int* dst = eidx + NE;

    assemble<<<181, 256, 0, stream>>>(l1aw, l1ab, l1bw, l1bb, l2aw, l2ab, l2bw, l2bb,
                                      W1, b1v, W2, b2v);

    // ---- CSR build (dst-sorted edge permutation, per half) ----
    zero_ints<<<(NN2 + 255) / 256, 256, 0, stream>>>(cur, NN2);
    count_edges<<<(NE + 255) / 256, 256, 0, stream>>>(dst, cur);
    scan_blocks<<<(NN2 + 255) / 256, 256, 0, stream>>>(cur, off, bsum, NN2);
    scan_bsum<<<1, 512, 0, stream>>>(bsum, (NN2 + 255) / 256);
    scan_add<<<(NN2 + 255) / 256, 256, 0, stream>>>(off, bsum, cur, NN2);
    scatter_edges<<<(NE + 255) / 256, 256, 0, stream>>>(dst, cur, perm);

    const int EG = (NN + RPB - 1) / RPB;   // edge-pass grid

    // ---- conv1 ----
    dim3 gNT1((NN + 63) / 64, (432 + 63) / 64);
    gemm_bias_act<<<gNT1, 256, 0, stream>>>(x, W1, b1v, NT, NN, 107, 432, 0);
    edge_pass<<<EG, 256, 0, stream>>>(eatt, eidx, perm, off, l1aw + 107 * 107, NT,
                                      x, bufA, 0, 0, 108, 432, 107, 0);
    edge_pass<<<EG, 256, 0, stream>>>(eatt, eidx, perm, off, l1bw + 107 * 107, NT,
                                      x, bufA, 1, 324, 216, 432, 107, 1);
    dim3 gM1((NN + 63) / 64, 2);
    gemm_bias_act<<<gM1, 256, 0, stream>>>(bufA, m1w1, m1b1, bufB, NN, 107, 100, 1);
    gemm_bias_act<<<gM1, 256, 0, stream>>>(bufB, m1w2, m1b2, bufC, NN, 100, 100, 1);

    // ---- conv2 ----  (h in bufC)
    dim3 gNT2((NN + 63) / 64, (416 + 63) / 64);
    gemm_bias_act<<<gNT2, 256, 0, stream>>>(bufC, W2, b2v, NT, NN, 100, 416, 0);
    edge_pass<<<EG, 256, 0, stream>>>(eatt, eidx, perm, off, l2aw + 100 * 100, NT,
                                      bufC, bufA, 0, 0, 104, 416, 100, 0);
    edge_pass<<<EG, 256, 0, stream>>>(eatt, eidx, perm, off, l2bw + 100 * 100, NT,
                                      bufC, bufA, 1, 312, 208, 416, 100, 1);
    dim3 gM2a((NN + 63) / 64, 1);
    gemm_bias_act<<<gM2a, 256, 0, stream>>>(bufA, m2w1, m2b1, bufB, NN, 100, 64, 1);
    dim3 gM2b((NN + 63) / 64, 2);
    gemm_bias_act<<<gM2b, 256, 0, stream>>>(bufB, m2w2, m2b2, out, NN, 64, 100, 0);
}

// Round 3
// 2027.959 us; speedup vs baseline: 1.8276x; 1.1171x over previous
//
#include <hip/hip_runtime.h>

// RuleGraphNet: 2x TripleConv(+mlp), N=50000 nodes, E=800000 edges.
// Edge mid-GEMM done with bf16 MFMA (16x16x32); W kept in registers as
// B-fragments; edge attrs staged bf16 in XOR-swizzled LDS; CSR-sorted edges,
// LDS accumulation, both conv halves fused into one dispatch.

#define NN 50000
#define NE 800000
#define EHALF 400000
#define NN2 100000
#define RPB 16          // dst nodes per block in edge pass (NN % RPB == 0)

typedef __attribute__((ext_vector_type(4))) float  f32x4;
typedef __attribute__((ext_vector_type(8))) __bf16 bf16x8;
typedef __attribute__((ext_vector_type(4))) __bf16 bf16x4;

// ---------------- generic fused GEMM: C = act(A@B + bias) ----------------
__global__ __launch_bounds__(256)
void gemm_bias_act(const float* __restrict__ A, const float* __restrict__ B,
                   const float* __restrict__ bias, float* __restrict__ C,
                   int M, int K, int Nc, int relu)
{
    __shared__ float As[32][68];
    __shared__ float Bs[32][68];
    const int t = threadIdx.x;
    const int tx = t & 15, ty = t >> 4;
    const int row0 = blockIdx.x * 64, col0 = blockIdx.y * 64;
    float acc[4][4] = {};
    for (int k0 = 0; k0 < K; k0 += 32) {
        for (int i = t; i < 2048; i += 256) {
            int r = i >> 5, kk = i & 31;
            int gr = row0 + r, gk = k0 + kk;
            As[kk][r] = (gr < M && gk < K) ? A[(size_t)gr * K + gk] : 0.f;
        }
        for (int i = t; i < 2048; i += 256) {
            int kk = i >> 6, c = i & 63;
            int gk = k0 + kk, gc = col0 + c;
            Bs[kk][c] = (gk < K && gc < Nc) ? B[(size_t)gk * Nc + gc] : 0.f;
        }
        __syncthreads();
        #pragma unroll
        for (int kk = 0; kk < 32; kk++) {
            float4 av = *(const float4*)&As[kk][ty * 4];
            float4 bv = *(const float4*)&Bs[kk][tx * 4];
            float a[4] = {av.x, av.y, av.z, av.w};
            float b[4] = {bv.x, bv.y, bv.z, bv.w};
            #pragma unroll
            for (int i = 0; i < 4; i++)
                #pragma unroll
                for (int j = 0; j < 4; j++)
                    acc[i][j] = fmaf(a[i], b[j], acc[i][j]);
        }
        __syncthreads();
    }
    #pragma unroll
    for (int i = 0; i < 4; i++) {
        int gr = row0 + ty * 4 + i;
        if (gr >= M) continue;
        #pragma unroll
        for (int j = 0; j < 4; j++) {
            int gc = col0 + tx * 4 + j;
            if (gc >= Nc) continue;
            float v = acc[i][j] + bias[gc];
            if (relu) v = fmaxf(v, 0.f);
            C[(size_t)gr * Nc + gc] = v;
        }
    }
}

// ---------------- CSR build (each call; edges sorted by dst, per half) ----
__global__ void zero_ints(int* __restrict__ p, int n)
{
    int i = blockIdx.x * 256 + threadIdx.x;
    if (i < n) p[i] = 0;
}

__global__ void count_edges(const int* __restrict__ dst, int* __restrict__ cnt)
{
    int e = blockIdx.x * 256 + threadIdx.x;
    if (e < NE) atomicAdd(&cnt[dst[e] + (e >= EHALF ? NN : 0)], 1);
}

__global__ void scan_blocks(const int* __restrict__ cnt, int* __restrict__ off,
                            int* __restrict__ bsum, int n)
{
    __shared__ int s[256];
    int t = threadIdx.x, g = blockIdx.x * 256 + t;
    int v = (g < n) ? cnt[g] : 0;
    s[t] = v; __syncthreads();
    for (int d = 1; d < 256; d <<= 1) {
        int add = (t >= d) ? s[t - d] : 0;
        __syncthreads();
        s[t] += add;
        __syncthreads();
    }
    if (g < n) off[g] = s[t] - v;
    if (t == 255) bsum[blockIdx.x] = s[255];
}

__global__ void scan_bsum(int* __restrict__ bsum, int nb)
{
    __shared__ int s[512];
    int t = threadIdx.x;
    int v = (t < nb) ? bsum[t] : 0;
    s[t] = v; __syncthreads();
    for (int d = 1; d < 512; d <<= 1) {
        int add = (t >= d) ? s[t - d] : 0;
        __syncthreads();
        s[t] += add;
        __syncthreads();
    }
    if (t < nb) bsum[t] = s[t] - v;
}

__global__ void scan_add(int* __restrict__ off, const int* __restrict__ bsum,
                         int* __restrict__ cur, int n)
{
    int g = blockIdx.x * 256 + threadIdx.x;
    if (g < n) { int o = off[g] + bsum[blockIdx.x]; off[g] = o; cur[g] = o; }
}

__global__ void scatter_edges(const int* __restrict__ dst, int* __restrict__ cur,
                              int* __restrict__ perm)
{
    int e = blockIdx.x * 256 + threadIdx.x;
    if (e < NE) {
        int pos = atomicAdd(&cur[dst[e] + (e >= EHALF ? NN : 0)], 1);
        perm[pos] = e;
    }
}

// ---------------- MFMA edge pass (both halves fused) ----------------
// Block owns RPB consecutive dst nodes. Per 32-edge tile, per wave:
//   A = et[m*16..+15][k]  (bf16, swizzled LDS), B = W-frags in registers,
//   C[edge][col] += A@B via 16 mfma_f32_16x16x32_bf16.
// Epilogue: m = relu(C + NT[dst][blkd+col] + NT[src][blks+col]), LDS-accumulate
// by node, single write at end fusing the self term.
__global__ __launch_bounds__(256, 3)
void edge_mfma(const float* __restrict__ eattr,   // [E][100]
               const int* __restrict__ eidx,      // [2][E]
               const int* __restrict__ perm,
               const int* __restrict__ off,       // [NN2] exclusive offsets
               const float* __restrict__ Wa,      // [100][ND] tight (half a)
               const float* __restrict__ Wb,      // [100][ND] tight (half b)
               const float* __restrict__ NT,      // [NN][NTS]
               const float* __restrict__ self,    // [NN][ND]
               float* __restrict__ aggr,          // [NN][ND]
               int blkd_a, int blks_a, int blkd_b, int blks_b, int NTS, int ND)
{
    __shared__ __align__(16) __bf16 et[32 * 128];   // 8 KB, XOR-swizzled
    __shared__ __align__(16) float accl[RPB * 128]; // 8 KB
    __shared__ int eid[32], esrc[32], edst[32];
    const int t = threadIdx.x;
    const int lane = t & 63, w = t >> 6;
    const int m = w & 1, g = w >> 1;
    const int l15 = lane & 15, l4 = lane >> 4;
    const int n0node = blockIdx.x * RPB;

    for (int i = t; i < RPB * 128; i += 256) accl[i] = 0.f;

    for (int phase = 0; phase < 2; ++phase) {
        const float* Wm = phase ? Wb : Wa;
        const int blkd = phase ? blkd_b : blkd_a;
        const int blks = phase ? blks_b : blks_a;

        // B-fragments in registers: wf[q][ks], col = (g*4+q)*16 + l15,
        // k = ks*32 + l4*8 + j  (zero-pad k>=100 or col>=ND)
        bf16x8 wf[4][4];
        const int wcolbase = (g * 4) * 16 + l15;
        #pragma unroll
        for (int q = 0; q < 4; ++q) {
            int col = wcolbase + q * 16;
            #pragma unroll
            for (int ks = 0; ks < 4; ++ks) {
                bf16x8 f;
                #pragma unroll
                for (int j = 0; j < 8; ++j) {
                    int k = ks * 32 + l4 * 8 + j;
                    float v = (k < 100 && col < ND) ? Wm[k * ND + col] : 0.f;
                    f[j] = (__bf16)v;
                }
                wf[q][ks] = f;
            }
        }

        const int base = phase * NN + n0node;
        const int p0 = off[base];
        const int p1 = (base + RPB == NN2) ? NE : off[base + RPB];

        for (int pt = p0; pt < p1; pt += 32) {
            __syncthreads();   // protect et/eid reuse (and accl init first iter)
            if (t < 32) {
                int p = pt + t;
                int e = (p < p1) ? perm[p] : -1;
                eid[t] = e;
                esrc[t] = (e >= 0) ? eidx[e] : -1;
                edst[t] = (e >= 0) ? eidx[NE + e] : -1;
            }
            __syncthreads();
            // stage 32 edges x 100 attrs as bf16 into swizzled LDS
            for (int i = t; i < 800; i += 256) {
                int el = i / 25, q = i - el * 25;     // row-grouped: coalesced
                int e = eid[el];
                float4 v = {0.f, 0.f, 0.f, 0.f};
                if (e >= 0) v = *(const float4*)(eattr + (size_t)e * 100 + q * 4);
                bf16x4 b;
                b[0] = (__bf16)v.x; b[1] = (__bf16)v.y;
                b[2] = (__bf16)v.z; b[3] = (__bf16)v.w;
                *(bf16x4*)(et + el * 128 + ((q * 4) ^ ((el & 7) << 3))) = b;
            }
            for (int i = t; i < 224; i += 256) {      // zero-pad k=100..127
                int el = i & 31, q7 = i >> 5;
                bf16x4 z; z[0] = (__bf16)0.f; z[1] = (__bf16)0.f;
                z[2] = (__bf16)0.f; z[3] = (__bf16)0.f;
                *(bf16x4*)(et + el * 128 + ((100 + q7 * 4) ^ ((el & 7) << 3))) = z;
            }
            __syncthreads();

            // 16 MFMAs: m-half edges x 4 n-tiles x 4 k-steps
            f32x4 c[4] = {};
            const int arow = m * 16 + l15;
            const int abase = arow * 128;
            const int aswz = (arow & 7) << 3;
            #pragma unroll
            for (int ks = 0; ks < 4; ++ks) {
                bf16x8 a = *(const bf16x8*)(et + abase + ((ks * 32 + l4 * 8) ^ aswz));
                c[0] = __builtin_amdgcn_mfma_f32_16x16x32_bf16(a, wf[0][ks], c[0], 0, 0, 0);
                c[1] = __builtin_amdgcn_mfma_f32_16x16x32_bf16(a, wf[1][ks], c[1], 0, 0, 0);
                c[2] = __builtin_amdgcn_mfma_f32_16x16x32_bf16(a, wf[2][ks], c[2], 0, 0, 0);
                c[3] = __builtin_amdgcn_mfma_f32_16x16x32_bf16(a, wf[3][ks], c[3], 0, 0, 0);
            }

            // epilogue: gather NT, relu, run-merge, LDS accumulate
            #pragma unroll
            for (int q = 0; q < 4; ++q) {
                int col = wcolbase + q * 16;
                if (col < ND) {
                    const float* NTd = NT + blkd + col;
                    const float* NTs = NT + blks + col;
                    int rd = -1; float run = 0.f;
                    #pragma unroll
                    for (int r = 0; r < 4; ++r) {
                        int el = m * 16 + l4 * 4 + r;
                        int d = edst[el];
                        if (d >= 0) {
                            float v = c[q][r] + NTd[(size_t)d * NTS]
                                             + NTs[(size_t)esrc[el] * NTS];
                            v = fmaxf(v, 0.f);
                            if (d == rd) run += v;
                            else {
                                if (rd >= 0) atomicAdd(&accl[(rd - n0node) * 128 + col], run);
                                rd = d; run = v;
                            }
                        }
                    }
                    if (rd >= 0) atomicAdd(&accl[(rd - n0node) * 128 + col], run);
                }
            }
        }
    }
    __syncthreads();
    const int tot = RPB * ND;
    for (int i = t; i < tot; i += 256) {
        int n = i / ND, cl = i - n * ND;
        size_t gi = (size_t)(n0node + n) * ND + cl;
        aggr[gi] = accl[n * 128 + cl] + self[gi];
    }
}

// ---------------- weight assembly (padded, 16B-aligned column blocks) -----
__global__ void assemble(const float* __restrict__ l1a, const float* __restrict__ l1ab,
                         const float* __restrict__ l1b, const float* __restrict__ l1bb,
                         const float* __restrict__ l2a, const float* __restrict__ l2ab,
                         const float* __restrict__ l2b, const float* __restrict__ l2bb,
                         float* __restrict__ W1, float* __restrict__ b1,
                         float* __restrict__ W2, float* __restrict__ b2)
{
    int i = blockIdx.x * 256 + threadIdx.x;
    if (i < 107 * 432) {
        int k = i / 432, c = i % 432;
        int q = c / 108, cc = c - q * 108;
        float v = 0.f;
        if (cc < 107) {
            if (q == 0)      v = l1a[k * 107 + cc];
            else if (q == 1) v = l1a[(207 + k) * 107 + cc];
            else if (q == 2) v = l1b[k * 107 + cc];
            else             v = l1b[(207 + k) * 107 + cc];
        }
        W1[i] = v;
    }
    if (i < 432) {
        int q = i / 108, cc = i - q * 108;
        b1[i] = (cc < 107) ? (q == 0 ? l1ab[cc] : (q == 3 ? l1bb[cc] : 0.f)) : 0.f;
    }
    if (i < 100 * 416) {
        int k = i / 416, c = i % 416;
        int q = c / 104, cc = c - q * 104;
        float v = 0.f;
        if (cc < 100) {
            if (q == 0)      v = l2a[k * 100 + cc];
            else if (q == 1) v = l2a[(200 + k) * 100 + cc];
            else if (q == 2) v = l2b[k * 100 + cc];
            else             v = l2b[(200 + k) * 100 + cc];
        }
        W2[i] = v;
    }
    if (i < 416) {
        int q = i / 104, cc = i - q * 104;
        b2[i] = (cc < 100) ? (q == 0 ? l2ab[cc] : (q == 3 ? l2bb[cc] : 0.f)) : 0.f;
    }
}

extern "C" void kernel_launch(void* const* d_in, const int* in_sizes, int n_in,
                              void* d_out, int out_size, void* d_ws, size_t ws_size,
                              hipStream_t stream)
{
    const float* x    = (const float*)d_in[0];
    const int*   eidx = (const int*)d_in[1];
    const float* eatt = (const float*)d_in[2];
    const float* l1aw = (const float*)d_in[3];
    const float* l1ab = (const float*)d_in[4];
    const float* l1bw = (const float*)d_in[5];
    const float* l1bb = (const float*)d_in[6];
    const float* m1w1 = (const float*)d_in[7];
    const float* m1b1 = (const float*)d_in[8];
    const float* m1w2 = (const float*)d_in[9];
    const float* m1b2 = (const float*)d_in[10];
    const float* l2aw = (const float*)d_in[11];
    const float* l2ab = (const float*)d_in[12];
    const float* l2bw = (const float*)d_in[13];
    const float* l2bb = (const float*)d_in[14];
    const float* m2w1 = (const float*)d_in[15];
    const float* m2b1 = (const float*)d_in[16];
    const float* m2w2 = (const float*)d_in[17];
    const float* m2b2 = (const float*)d_in[18];
    float* out = (float*)d_out;

    // workspace layout (4-byte units)
    float* ws   = (float*)d_ws;
    float* NT   = ws;                                   // 50000*432 = 21,600,000
    float* bufA = NT + (size_t)50000 * 432;             // 5,350,000 (aggr1, aggr2)
    float* bufB = bufA + 5350000;                       // 5,000,000 (t1, t2)
    float* bufC = bufB + 5000000;                       // 5,000,000 (h)
    float* W1   = bufC + 5000000;                       // 46,224
    float* b1v  = W1 + 46224;                           // 432
    float* W2   = b1v + 432;                            // 41,600
    float* b2v  = W2 + 41600;                           // 416
    int*   off  = (int*)(b2v + 416);                    // 100,000
    int*   cur  = off + NN2;                            // 100,000
    int*   bsum = cur + NN2;                            // 512
    int*   perm = bsum + 512;                           // 800,000

    const int* dst = eidx + NE;

    assemble<<<181, 256, 0, stream>>>(l1aw, l1ab, l1bw, l1bb, l2aw, l2ab, l2bw, l2bb,
                                      W1, b1v, W2, b2v);

    // ---- CSR build (dst-sorted edge permutation, per half) ----
    zero_ints<<<(NN2 + 255) / 256, 256, 0, stream>>>(cur, NN2);
    count_edges<<<(NE + 255) / 256, 256, 0, stream>>>(dst, cur);
    scan_blocks<<<(NN2 + 255) / 256, 256, 0, stream>>>(cur, off, bsum, NN2);
    scan_bsum<<<1, 512, 0, stream>>>(bsum, (NN2 + 255) / 256);
    scan_add<<<(NN2 + 255) / 256, 256, 0, stream>>>(off, bsum, cur, NN2);
    scatter_edges<<<(NE + 255) / 256, 256, 0, stream>>>(dst, cur, perm);

    const int EG = NN / RPB;   // 3125

    // ---- conv1 ----
    dim3 gNT1((NN + 63) / 64, (432 + 63) / 64);
    gemm_bias_act<<<gNT1, 256, 0, stream>>>(x, W1, b1v, NT, NN, 107, 432, 0);
    edge_mfma<<<EG, 256, 0, stream>>>(eatt, eidx, perm, off,
                                      l1aw + 107 * 107, l1bw + 107 * 107,
                                      NT, x, bufA, 0, 108, 324, 216, 432, 107);
    dim3 gM1((NN + 63) / 64, 2);
    gemm_bias_act<<<gM1, 256, 0, stream>>>(bufA, m1w1, m1b1, bufB, NN, 107, 100, 1);
    gemm_bias_act<<<gM1, 256, 0, stream>>>(bufB, m1w2, m1b2, bufC, NN, 100, 100, 1);

    // ---- conv2 ----  (h in bufC)
    dim3 gNT2((NN + 63) / 64, (416 + 63) / 64);
    gemm_bias_act<<<gNT2, 256, 0, stream>>>(bufC, W2, b2v, NT, NN, 100, 416, 0);
    edge_mfma<<<EG, 256, 0, stream>>>(eatt, eidx, perm, off,
                                      l2aw + 100 * 100, l2bw + 100 * 100,
                                      NT, bufC, bufA, 0, 104, 312, 208, 416, 100);
    dim3 gM2a((NN + 63) / 64, 1);
    gemm_bias_act<<<gM2a, 256, 0, stream>>>(bufA, m2w1, m2b1, bufB, NN, 100, 64, 1);
    dim3 gM2b((NN + 63) / 64, 2);
    gemm_bias_act<<<gM2b, 256, 0, stream>>>(bufB, m2w2, m2b2, out, NN, 64, 100, 0);
}